// Round 1
// baseline (2020.041 us; speedup 1.0000x reference)
//
#include <hip/hip_runtime.h>
#include <hip/hip_bf16.h>
#include <cstddef>

// ---------------------------------------------------------------------------
// Generic tiled SGEMM: C[M,N] = A[M,K] @ W[N,K]^T (+bias) (+=C if accum)
// BM=BN=64, BK=16, 256 threads, 4x4 per thread. LDS padded to 68 (bank-safe,
// 16B-aligned rows for b128 reads).
// ---------------------------------------------------------------------------
#define BM 64
#define BN 64
#define BK 16
#define LPAD 68

__global__ __launch_bounds__(256) void gemm_nt(
    const float* __restrict__ A, const float* __restrict__ W,
    const float* __restrict__ bias, float* __restrict__ C,
    int M, int N, int K, int ldc, int accum)
{
    __shared__ float As[BK][LPAD];
    __shared__ float Ws[BK][LPAD];
    const int tid = threadIdx.x;
    const int n0 = blockIdx.x * BN;
    const int m0 = blockIdx.y * BM;
    const int kk = tid & 15;   // k within tile
    const int rr = tid >> 4;   // row group
    const int ty = tid >> 4;   // m sub-tile
    const int tx = tid & 15;   // n sub-tile
    float acc[4][4] = {};

    for (int k0 = 0; k0 < K; k0 += BK) {
        #pragma unroll
        for (int p = 0; p < 4; ++p) {
            int row = rr + p * 16;
            int m = m0 + row;
            int n = n0 + row;
            As[kk][row] = (m < M) ? A[(size_t)m * K + k0 + kk] : 0.f;
            Ws[kk][row] = (n < N) ? W[(size_t)n * K + k0 + kk] : 0.f;
        }
        __syncthreads();
        #pragma unroll
        for (int k = 0; k < BK; ++k) {
            float a[4], b[4];
            #pragma unroll
            for (int i = 0; i < 4; ++i) a[i] = As[k][ty * 4 + i];
            #pragma unroll
            for (int j = 0; j < 4; ++j) b[j] = Ws[k][tx * 4 + j];
            #pragma unroll
            for (int i = 0; i < 4; ++i)
                #pragma unroll
                for (int j = 0; j < 4; ++j)
                    acc[i][j] += a[i] * b[j];
        }
        __syncthreads();
    }

    #pragma unroll
    for (int i = 0; i < 4; ++i) {
        int m = m0 + ty * 4 + i;
        if (m >= M) continue;
        #pragma unroll
        for (int j = 0; j < 4; ++j) {
            int n = n0 + tx * 4 + j;
            if (n >= N) continue;
            float v = acc[i][j];
            if (bias) v += bias[n];
            size_t off = (size_t)m * ldc + n;
            if (accum) C[off] += v; else C[off] = v;
        }
    }
}

// ---------------------------------------------------------------------------
// Bahdanau attention tail: scores = tanh(v1[b,:] + v2[b,t,:]) . W3 ;
// softmax over t ; out[b,:] = sum_t attn[t] * enc[b,t,:]
// One block (256 thr = 4 waves) per batch row. C fixed at 512.
// ---------------------------------------------------------------------------
__global__ __launch_bounds__(256) void attend_kernel(
    const float* __restrict__ v1, const float* __restrict__ v2,
    const float* __restrict__ W3, const float* __restrict__ enc,
    float* __restrict__ out, int T, int E)
{
    const int C = 512;
    __shared__ float sc[128];
    const int b = blockIdx.x, tid = threadIdx.x;
    const int lane = tid & 63, wave = tid >> 6;
    const float* v1b = v1 + (size_t)b * C;

    for (int t = wave; t < T; t += 4) {
        const float* v2p = v2 + ((size_t)b * T + t) * C;
        float s = 0.f;
        for (int c = lane; c < C; c += 64)
            s += tanhf(v1b[c] + v2p[c]) * W3[c];
        #pragma unroll
        for (int off = 32; off; off >>= 1) s += __shfl_down(s, off, 64);
        if (lane == 0) sc[t] = s;
    }
    __syncthreads();

    if (wave == 0) {
        float a0 = sc[lane];
        float a1 = (T > 64) ? sc[lane + 64] : -1e30f;
        float m = fmaxf(a0, a1);
        #pragma unroll
        for (int off = 32; off; off >>= 1) m = fmaxf(m, __shfl_xor(m, off, 64));
        float e0 = __expf(a0 - m);
        float e1 = (T > 64) ? __expf(a1 - m) : 0.f;
        float s = e0 + e1;
        #pragma unroll
        for (int off = 32; off; off >>= 1) s += __shfl_xor(s, off, 64);
        float inv = 1.f / s;
        sc[lane] = e0 * inv;
        if (T > 64) sc[lane + 64] = e1 * inv;
    }
    __syncthreads();

    const float* encb = enc + (size_t)b * T * E;
    for (int e = tid; e < E; e += 256) {
        float acc = 0.f;
        for (int t = 0; t < T; ++t)
            acc += sc[t] * encb[(size_t)t * E + e];
        out[(size_t)b * E + e] = acc;
    }
}

// ---------------------------------------------------------------------------
// Cross-modal attention over the 2 context vectors + build RNN input x:
// x[b, 0:512]    = input[b,:]
// x[b, 512:1024] = tanh( a0*ctx[b,0,:] + a1*ctx[b,1,:] )
// ---------------------------------------------------------------------------
__global__ __launch_bounds__(256) void cross_kernel(
    const float* __restrict__ hc1, const float* __restrict__ v2c,
    const float* __restrict__ W3, const float* __restrict__ ctx,
    const float* __restrict__ inp, float* __restrict__ x)
{
    const int C = 512;
    __shared__ float red[256];
    __shared__ float aw[2];
    const int b = blockIdx.x, tid = threadIdx.x;

    float p0 = 0.f, p1 = 0.f;
    for (int c = tid; c < C; c += 256) {
        float h = hc1[(size_t)b * C + c], w = W3[c];
        p0 += tanhf(h + v2c[(size_t)(b * 2 + 0) * C + c]) * w;
        p1 += tanhf(h + v2c[(size_t)(b * 2 + 1) * C + c]) * w;
    }
    red[tid] = p0; __syncthreads();
    for (int s = 128; s; s >>= 1) { if (tid < s) red[tid] += red[tid + s]; __syncthreads(); }
    float s0 = red[0];
    __syncthreads();
    red[tid] = p1; __syncthreads();
    for (int s = 128; s; s >>= 1) { if (tid < s) red[tid] += red[tid + s]; __syncthreads(); }
    if (tid == 0) {
        float s1 = red[0];
        float m = fmaxf(s0, s1);
        float e0 = __expf(s0 - m), e1 = __expf(s1 - m);
        float inv = 1.f / (e0 + e1);
        aw[0] = e0 * inv; aw[1] = e1 * inv;
    }
    __syncthreads();
    float a0 = aw[0], a1 = aw[1];
    for (int c = tid; c < C; c += 256) {
        float fc = a0 * ctx[(size_t)(b * 2 + 0) * C + c]
                 + a1 * ctx[(size_t)(b * 2 + 1) * C + c];
        x[(size_t)b * 1024 + 512 + c] = tanhf(fc);
        x[(size_t)b * 1024 + c] = inp[(size_t)b * 512 + c];
    }
}

// ---------------------------------------------------------------------------
// LSTM pointwise: gates[B,4H] (i,f,g,o) -> h_new, c_new
// ---------------------------------------------------------------------------
__global__ __launch_bounds__(256) void lstm_kernel(
    const float* __restrict__ gates, const float* __restrict__ c0,
    float* __restrict__ hout, float* __restrict__ cout)
{
    const int idx = blockIdx.x * 256 + threadIdx.x;   // over B*H = 131072
    const int b = idx >> 10, h = idx & 1023;
    const float* g = gates + (size_t)b * 4096;
    float gi = g[h], gf = g[1024 + h], gg = g[2048 + h], go = g[3072 + h];
    float si = 1.f / (1.f + __expf(-gi));
    float sf = 1.f / (1.f + __expf(-gf));
    float so = 1.f / (1.f + __expf(-go));
    float cn = sf * c0[idx] + si * tanhf(gg);
    float hn = so * tanhf(cn);
    cout[idx] = cn;
    hout[idx] = hn;
}

// ---------------------------------------------------------------------------
extern "C" void kernel_launch(void* const* d_in, const int* in_sizes, int n_in,
                              void* d_out, int out_size, void* d_ws, size_t ws_size,
                              hipStream_t stream)
{
    const float* inp    = (const float*)d_in[0];
    const float* encv   = (const float*)d_in[1];
    const float* enca   = (const float*)d_in[2];
    const float* h0     = (const float*)d_in[3];
    const float* c0     = (const float*)d_in[4];
    const float* W_va1  = (const float*)d_in[5];
    const float* W_va2  = (const float*)d_in[6];
    const float* W_va3  = (const float*)d_in[7];
    const float* W_venc = (const float*)d_in[8];
    const float* W_aa1  = (const float*)d_in[9];
    const float* W_aa2  = (const float*)d_in[10];
    const float* W_aa3  = (const float*)d_in[11];
    const float* W_aenc = (const float*)d_in[12];
    const float* W_ca1  = (const float*)d_in[13];
    const float* W_ca2  = (const float*)d_in[14];
    const float* W_ca3  = (const float*)d_in[15];
    const float* W_ih   = (const float*)d_in[16];
    const float* W_hh   = (const float*)d_in[17];
    const float* b_ih   = (const float*)d_in[18];
    const float* b_hh   = (const float*)d_in[19];
    const float* W_out  = (const float*)d_in[20];
    const float* b_out  = (const float*)d_in[21];
    float* out = (float*)d_out;

    float* ws = (float*)d_ws;
    float* v2v  = ws;  ws += (size_t)128 * 64 * 512;    // [B*T_V, C]
    float* v2a  = ws;  ws += (size_t)128 * 128 * 512;   // [B*T_A, C]
    float* hv1  = ws;  ws += 128 * 512;
    float* ha1  = ws;  ws += 128 * 512;
    float* hc1  = ws;  ws += 128 * 512;
    float* attv = ws;  ws += 128 * 1024;                // attended enc_visual [B,E_V]
    float* atta = ws;  ws += 128 * 512;                 // attended enc_audio  [B,E_A]
    float* ctx  = ws;  ws += 128 * 2 * 512;             // [B,2,C]: vc | ac
    float* v2c  = ws;  ws += 128 * 2 * 512;
    float* xb   = ws;  ws += 128 * 1024;                // RNN input [B,IN]
    float* gates= ws;  ws += (size_t)128 * 4096;

    dim3 blk(256);
    auto g = [](int N, int M) { return dim3((unsigned)((N + 63) / 64), (unsigned)((M + 63) / 64)); };

    // h0 projections for the three attentions
    gemm_nt<<<g(512, 128), blk, 0, stream>>>(h0, W_va1, nullptr, hv1, 128, 512, 1024, 512, 0);
    gemm_nt<<<g(512, 128), blk, 0, stream>>>(h0, W_aa1, nullptr, ha1, 128, 512, 1024, 512, 0);
    gemm_nt<<<g(512, 128), blk, 0, stream>>>(h0, W_ca1, nullptr, hc1, 128, 512, 1024, 512, 0);
    // encoder projections (the two big GEMMs)
    gemm_nt<<<g(512, 8192), blk, 0, stream>>>(encv, W_va2, nullptr, v2v, 8192, 512, 1024, 512, 0);
    gemm_nt<<<g(512, 16384), blk, 0, stream>>>(enca, W_aa2, nullptr, v2a, 16384, 512, 512, 512, 0);
    // attention score + softmax + weighted encoder sum
    attend_kernel<<<128, blk, 0, stream>>>(hv1, v2v, W_va3, encv, attv, 64, 1024);
    attend_kernel<<<128, blk, 0, stream>>>(ha1, v2a, W_aa3, enca, atta, 128, 512);
    // context projections, written interleaved into ctx[B,2,C]
    gemm_nt<<<g(512, 128), blk, 0, stream>>>(attv, W_venc, nullptr, ctx,       128, 512, 1024, 1024, 0);
    gemm_nt<<<g(512, 128), blk, 0, stream>>>(atta, W_aenc, nullptr, ctx + 512, 128, 512,  512, 1024, 0);
    // cross-modal key projection: [B*2, C] @ W_ca2^T
    gemm_nt<<<g(512, 256), blk, 0, stream>>>(ctx, W_ca2, nullptr, v2c, 256, 512, 512, 512, 0);
    // cross-modal attention + build x = [input | tanh(final_ctx)]
    cross_kernel<<<128, blk, 0, stream>>>(hc1, v2c, W_ca3, ctx, inp, xb);
    // LSTM gates: x@W_ih^T + b_ih, then += h0@W_hh^T + b_hh
    gemm_nt<<<g(4096, 128), blk, 0, stream>>>(xb, W_ih, b_ih, gates, 128, 4096, 1024, 4096, 0);
    gemm_nt<<<g(4096, 128), blk, 0, stream>>>(h0, W_hh, b_hh, gates, 128, 4096, 1024, 4096, 1);
    // LSTM pointwise -> h_new, c_new straight into d_out tail
    float* hout = out + 2560000;           // after logits [128,1,20000]
    float* cout = out + 2560000 + 131072;
    lstm_kernel<<<512, blk, 0, stream>>>(gates, c0, hout, cout);
    // logits = h_new @ W_out^T + b_out
    gemm_nt<<<g(20000, 128), blk, 0, stream>>>(hout, W_out, b_out, out, 128, 20000, 1024, 20000, 0);
}

// Round 2
// 1537.495 us; speedup vs baseline: 1.3139x; 1.3139x over previous
//
#include <hip/hip_runtime.h>
#include <hip/hip_bf16.h>
#include <cstddef>

// ===========================================================================
// bf16 MFMA GEMM:  C[M,N] = A[M,K] @ W[N,K]^T (+bias) (+=C if accum)
// 128x128 tile, BK=32, 256 threads (4 waves), each wave 64x64 via 4x4 of
// 16x16x32 MFMA. fp32 inputs converted to bf16 inline during LDS staging.
// Requires: M % 128 == 0, K % 32 == 0. N arbitrary (bounds-checked).
// ===========================================================================
typedef __attribute__((ext_vector_type(8))) short short8;   // 8 bf16 = 4 VGPR
typedef __attribute__((ext_vector_type(4))) float f32x4;

#define LSTR 40   // LDS row stride in bf16 elements (80 B -> 16B aligned, de-clustered banks)

static __device__ inline short f2bf(float x) {
    unsigned u = __float_as_uint(x);
    unsigned r = (u + 0x7FFF + ((u >> 16) & 1)) >> 16;   // RNE
    return (short)r;
}

__global__ __launch_bounds__(256) void gemm_mfma_bt(
    const float* __restrict__ A, const float* __restrict__ W,
    const float* __restrict__ bias, float* __restrict__ C,
    int M, int N, int K, int accum)
{
    __shared__ short As[128 * LSTR];
    __shared__ short Ws[128 * LSTR];
    const int tid  = threadIdx.x;
    const int lane = tid & 63;
    const int wave = tid >> 6;
    const int m0 = blockIdx.y * 128;
    const int n0 = blockIdx.x * 128;
    const int wm = (wave >> 1) * 64;      // wave row origin in tile
    const int wn = (wave & 1) * 64;       // wave col origin in tile

    f32x4 acc[4][4];
    #pragma unroll
    for (int i = 0; i < 4; ++i)
        #pragma unroll
        for (int j = 0; j < 4; ++j)
            acc[i][j] = (f32x4){0.f, 0.f, 0.f, 0.f};

    // staging: thread covers rows (tid>>2) and (tid>>2)+64, k-chunk (tid&3)*8
    const int srow  = tid >> 2;
    const int skoff = (tid & 3) * 8;
    // fragment read indices
    const int frow  = lane & 15;            // row/col within 16-tile
    const int fkoff = (lane >> 4) * 8;      // k offset of this lane's 8 elems

    for (int k0 = 0; k0 < K; k0 += 32) {
        #pragma unroll
        for (int p = 0; p < 2; ++p) {
            int row = srow + p * 64;
            // A tile (rows always in-bounds: M % 128 == 0)
            {
                const float* src = A + (size_t)(m0 + row) * K + k0 + skoff;
                float4 f0 = *(const float4*)(src);
                float4 f1 = *(const float4*)(src + 4);
                short8 v;
                v[0] = f2bf(f0.x); v[1] = f2bf(f0.y); v[2] = f2bf(f0.z); v[3] = f2bf(f0.w);
                v[4] = f2bf(f1.x); v[5] = f2bf(f1.y); v[6] = f2bf(f1.z); v[7] = f2bf(f1.w);
                *(short8*)(As + row * LSTR + skoff) = v;
            }
            // W tile (bounds-check rows vs N)
            {
                int n = n0 + row;
                short8 v = (short8){0,0,0,0,0,0,0,0};
                if (n < N) {
                    const float* src = W + (size_t)n * K + k0 + skoff;
                    float4 f0 = *(const float4*)(src);
                    float4 f1 = *(const float4*)(src + 4);
                    v[0] = f2bf(f0.x); v[1] = f2bf(f0.y); v[2] = f2bf(f0.z); v[3] = f2bf(f0.w);
                    v[4] = f2bf(f1.x); v[5] = f2bf(f1.y); v[6] = f2bf(f1.z); v[7] = f2bf(f1.w);
                }
                *(short8*)(Ws + row * LSTR + skoff) = v;
            }
        }
        __syncthreads();

        short8 af[4], bf[4];
        #pragma unroll
        for (int i = 0; i < 4; ++i)
            af[i] = *(const short8*)(As + (wm + i * 16 + frow) * LSTR + fkoff);
        #pragma unroll
        for (int j = 0; j < 4; ++j)
            bf[j] = *(const short8*)(Ws + (wn + j * 16 + frow) * LSTR + fkoff);
        #pragma unroll
        for (int i = 0; i < 4; ++i)
            #pragma unroll
            for (int j = 0; j < 4; ++j)
                acc[i][j] = __builtin_amdgcn_mfma_f32_16x16x32_bf16(af[i], bf[j], acc[i][j], 0, 0, 0);
        __syncthreads();
    }

    // epilogue: C/D layout col = lane&15, row = (lane>>4)*4 + reg
    const int cl = lane & 15;
    const int rq = (lane >> 4) * 4;
    #pragma unroll
    for (int i = 0; i < 4; ++i) {
        #pragma unroll
        for (int j = 0; j < 4; ++j) {
            int gc = n0 + wn + j * 16 + cl;
            if (gc >= N) continue;
            int gr = m0 + wm + i * 16 + rq;
            float b = bias ? bias[gc] : 0.f;
            #pragma unroll
            for (int r = 0; r < 4; ++r) {
                size_t off = (size_t)(gr + r) * N + gc;
                float v = acc[i][j][r] + b;
                if (accum) v += C[off];
                C[off] = v;
            }
        }
    }
}

// ---------------------------------------------------------------------------
// fp32 tiled SGEMM for the small projections (M=128-ish, N=512)
// ---------------------------------------------------------------------------
#define BM 64
#define BN 64
#define BK 16
#define LPAD 68

__global__ __launch_bounds__(256) void gemm_nt(
    const float* __restrict__ A, const float* __restrict__ W,
    const float* __restrict__ bias, float* __restrict__ C,
    int M, int N, int K, int ldc, int accum)
{
    __shared__ float As[BK][LPAD];
    __shared__ float Ws2[BK][LPAD];
    const int tid = threadIdx.x;
    const int n0 = blockIdx.x * BN;
    const int m0 = blockIdx.y * BM;
    const int kk = tid & 15;
    const int rr = tid >> 4;
    const int ty = tid >> 4;
    const int tx = tid & 15;
    float acc[4][4] = {};

    for (int k0 = 0; k0 < K; k0 += BK) {
        #pragma unroll
        for (int p = 0; p < 4; ++p) {
            int row = rr + p * 16;
            int m = m0 + row;
            int n = n0 + row;
            As[kk][row]  = (m < M) ? A[(size_t)m * K + k0 + kk] : 0.f;
            Ws2[kk][row] = (n < N) ? W[(size_t)n * K + k0 + kk] : 0.f;
        }
        __syncthreads();
        #pragma unroll
        for (int k = 0; k < BK; ++k) {
            float a[4], b[4];
            #pragma unroll
            for (int i = 0; i < 4; ++i) a[i] = As[k][ty * 4 + i];
            #pragma unroll
            for (int j = 0; j < 4; ++j) b[j] = Ws2[k][tx * 4 + j];
            #pragma unroll
            for (int i = 0; i < 4; ++i)
                #pragma unroll
                for (int j = 0; j < 4; ++j)
                    acc[i][j] += a[i] * b[j];
        }
        __syncthreads();
    }

    #pragma unroll
    for (int i = 0; i < 4; ++i) {
        int m = m0 + ty * 4 + i;
        if (m >= M) continue;
        #pragma unroll
        for (int j = 0; j < 4; ++j) {
            int n = n0 + tx * 4 + j;
            if (n >= N) continue;
            float v = acc[i][j];
            if (bias) v += bias[n];
            size_t off = (size_t)m * ldc + n;
            if (accum) C[off] += v; else C[off] = v;
        }
    }
}

// ---------------------------------------------------------------------------
// Bahdanau attention tail (one block per batch row)
// ---------------------------------------------------------------------------
__global__ __launch_bounds__(256) void attend_kernel(
    const float* __restrict__ v1, const float* __restrict__ v2,
    const float* __restrict__ W3, const float* __restrict__ enc,
    float* __restrict__ out, int T, int E)
{
    const int C = 512;
    __shared__ float sc[128];
    const int b = blockIdx.x, tid = threadIdx.x;
    const int lane = tid & 63, wave = tid >> 6;
    const float* v1b = v1 + (size_t)b * C;

    for (int t = wave; t < T; t += 4) {
        const float* v2p = v2 + ((size_t)b * T + t) * C;
        float s = 0.f;
        for (int c = lane; c < C; c += 64)
            s += tanhf(v1b[c] + v2p[c]) * W3[c];
        #pragma unroll
        for (int off = 32; off; off >>= 1) s += __shfl_down(s, off, 64);
        if (lane == 0) sc[t] = s;
    }
    __syncthreads();

    if (wave == 0) {
        float a0 = sc[lane];
        float a1 = (T > 64) ? sc[lane + 64] : -1e30f;
        float m = fmaxf(a0, a1);
        #pragma unroll
        for (int off = 32; off; off >>= 1) m = fmaxf(m, __shfl_xor(m, off, 64));
        float e0 = __expf(a0 - m);
        float e1 = (T > 64) ? __expf(a1 - m) : 0.f;
        float s = e0 + e1;
        #pragma unroll
        for (int off = 32; off; off >>= 1) s += __shfl_xor(s, off, 64);
        float inv = 1.f / s;
        sc[lane] = e0 * inv;
        if (T > 64) sc[lane + 64] = e1 * inv;
    }
    __syncthreads();

    const float* encb = enc + (size_t)b * T * E;
    for (int e = tid; e < E; e += 256) {
        float acc = 0.f;
        for (int t = 0; t < T; ++t)
            acc += sc[t] * encb[(size_t)t * E + e];
        out[(size_t)b * E + e] = acc;
    }
}

// ---------------------------------------------------------------------------
// Cross-modal attention + build x = [input | tanh(final_ctx)]
// ---------------------------------------------------------------------------
__global__ __launch_bounds__(256) void cross_kernel(
    const float* __restrict__ hc1, const float* __restrict__ v2c,
    const float* __restrict__ W3, const float* __restrict__ ctx,
    const float* __restrict__ inp, float* __restrict__ x)
{
    const int C = 512;
    __shared__ float red[256];
    __shared__ float aw[2];
    const int b = blockIdx.x, tid = threadIdx.x;

    float p0 = 0.f, p1 = 0.f;
    for (int c = tid; c < C; c += 256) {
        float h = hc1[(size_t)b * C + c], w = W3[c];
        p0 += tanhf(h + v2c[(size_t)(b * 2 + 0) * C + c]) * w;
        p1 += tanhf(h + v2c[(size_t)(b * 2 + 1) * C + c]) * w;
    }
    red[tid] = p0; __syncthreads();
    for (int s = 128; s; s >>= 1) { if (tid < s) red[tid] += red[tid + s]; __syncthreads(); }
    float s0 = red[0];
    __syncthreads();
    red[tid] = p1; __syncthreads();
    for (int s = 128; s; s >>= 1) { if (tid < s) red[tid] += red[tid + s]; __syncthreads(); }
    if (tid == 0) {
        float s1 = red[0];
        float m = fmaxf(s0, s1);
        float e0 = __expf(s0 - m), e1 = __expf(s1 - m);
        float inv = 1.f / (e0 + e1);
        aw[0] = e0 * inv; aw[1] = e1 * inv;
    }
    __syncthreads();
    float a0 = aw[0], a1 = aw[1];
    for (int c = tid; c < C; c += 256) {
        float fc = a0 * ctx[(size_t)(b * 2 + 0) * C + c]
                 + a1 * ctx[(size_t)(b * 2 + 1) * C + c];
        x[(size_t)b * 1024 + 512 + c] = tanhf(fc);
        x[(size_t)b * 1024 + c] = inp[(size_t)b * 512 + c];
    }
}

// ---------------------------------------------------------------------------
// LSTM pointwise
// ---------------------------------------------------------------------------
__global__ __launch_bounds__(256) void lstm_kernel(
    const float* __restrict__ gates, const float* __restrict__ c0,
    float* __restrict__ hout, float* __restrict__ cout)
{
    const int idx = blockIdx.x * 256 + threadIdx.x;   // B*H = 131072
    const int b = idx >> 10, h = idx & 1023;
    const float* g = gates + (size_t)b * 4096;
    float gi = g[h], gf = g[1024 + h], gg = g[2048 + h], go = g[3072 + h];
    float si = 1.f / (1.f + __expf(-gi));
    float sf = 1.f / (1.f + __expf(-gf));
    float so = 1.f / (1.f + __expf(-go));
    float cn = sf * c0[idx] + si * tanhf(gg);
    float hn = so * tanhf(cn);
    cout[idx] = cn;
    hout[idx] = hn;
}

// ---------------------------------------------------------------------------
extern "C" void kernel_launch(void* const* d_in, const int* in_sizes, int n_in,
                              void* d_out, int out_size, void* d_ws, size_t ws_size,
                              hipStream_t stream)
{
    const float* inp    = (const float*)d_in[0];
    const float* encv   = (const float*)d_in[1];
    const float* enca   = (const float*)d_in[2];
    const float* h0     = (const float*)d_in[3];
    const float* c0     = (const float*)d_in[4];
    const float* W_va1  = (const float*)d_in[5];
    const float* W_va2  = (const float*)d_in[6];
    const float* W_va3  = (const float*)d_in[7];
    const float* W_venc = (const float*)d_in[8];
    const float* W_aa1  = (const float*)d_in[9];
    const float* W_aa2  = (const float*)d_in[10];
    const float* W_aa3  = (const float*)d_in[11];
    const float* W_aenc = (const float*)d_in[12];
    const float* W_ca1  = (const float*)d_in[13];
    const float* W_ca2  = (const float*)d_in[14];
    const float* W_ca3  = (const float*)d_in[15];
    const float* W_ih   = (const float*)d_in[16];
    const float* W_hh   = (const float*)d_in[17];
    const float* b_ih   = (const float*)d_in[18];
    const float* b_hh   = (const float*)d_in[19];
    const float* W_out  = (const float*)d_in[20];
    const float* b_out  = (const float*)d_in[21];
    float* out = (float*)d_out;

    float* ws = (float*)d_ws;
    float* v2v  = ws;  ws += (size_t)128 * 64 * 512;    // [B*T_V, C]
    float* v2a  = ws;  ws += (size_t)128 * 128 * 512;   // [B*T_A, C]
    float* hv1  = ws;  ws += 128 * 512;
    float* ha1  = ws;  ws += 128 * 512;
    float* hc1  = ws;  ws += 128 * 512;
    float* attv = ws;  ws += 128 * 1024;
    float* atta = ws;  ws += 128 * 512;
    float* ctx  = ws;  ws += 128 * 2 * 512;
    float* v2c  = ws;  ws += 128 * 2 * 512;
    float* xb   = ws;  ws += 128 * 1024;
    float* gates= ws;  ws += (size_t)128 * 4096;

    dim3 blk(256);
    auto g  = [](int N, int M) { return dim3((unsigned)((N + 63) / 64), (unsigned)((M + 63) / 64)); };
    auto gm = [](int N, int M) { return dim3((unsigned)((N + 127) / 128), (unsigned)(M / 128)); };

    // h0 projections (small, fp32)
    gemm_nt<<<g(512, 128), blk, 0, stream>>>(h0, W_va1, nullptr, hv1, 128, 512, 1024, 512, 0);
    gemm_nt<<<g(512, 128), blk, 0, stream>>>(h0, W_aa1, nullptr, ha1, 128, 512, 1024, 512, 0);
    gemm_nt<<<g(512, 128), blk, 0, stream>>>(h0, W_ca1, nullptr, hc1, 128, 512, 1024, 512, 0);
    // encoder projections — bf16 MFMA
    gemm_mfma_bt<<<gm(512, 8192),  blk, 0, stream>>>(encv, W_va2, nullptr, v2v, 8192,  512, 1024, 0);
    gemm_mfma_bt<<<gm(512, 16384), blk, 0, stream>>>(enca, W_aa2, nullptr, v2a, 16384, 512,  512, 0);
    // attention tails
    attend_kernel<<<128, blk, 0, stream>>>(hv1, v2v, W_va3, encv, attv, 64, 1024);
    attend_kernel<<<128, blk, 0, stream>>>(ha1, v2a, W_aa3, enca, atta, 128, 512);
    // context projections (small, fp32), interleaved into ctx[B,2,C]
    gemm_nt<<<g(512, 128), blk, 0, stream>>>(attv, W_venc, nullptr, ctx,       128, 512, 1024, 1024, 0);
    gemm_nt<<<g(512, 128), blk, 0, stream>>>(atta, W_aenc, nullptr, ctx + 512, 128, 512,  512, 1024, 0);
    // cross-modal key projection
    gemm_nt<<<g(512, 256), blk, 0, stream>>>(ctx, W_ca2, nullptr, v2c, 256, 512, 512, 512, 0);
    // cross-modal attention + x build
    cross_kernel<<<128, blk, 0, stream>>>(hc1, v2c, W_ca3, ctx, inp, xb);
    // LSTM gates — bf16 MFMA, second accumulates
    gemm_mfma_bt<<<gm(4096, 128), blk, 0, stream>>>(xb, W_ih, b_ih, gates, 128, 4096, 1024, 0);
    gemm_mfma_bt<<<gm(4096, 128), blk, 0, stream>>>(h0, W_hh, b_hh, gates, 128, 4096, 1024, 1);
    // LSTM pointwise -> h_new, c_new in d_out tail
    float* hout = out + 2560000;
    float* cout = out + 2560000 + 131072;
    lstm_kernel<<<512, blk, 0, stream>>>(gates, c0, hout, cout);
    // logits — bf16 MFMA
    gemm_mfma_bt<<<gm(20000, 128), blk, 0, stream>>>(hout, W_out, b_out, out, 128, 20000, 1024, 0);
}

// Round 3
// 694.271 us; speedup vs baseline: 2.9096x; 2.2145x over previous
//
#include <hip/hip_runtime.h>
#include <hip/hip_bf16.h>
#include <cstddef>

typedef __attribute__((ext_vector_type(8))) short short8;   // 8 bf16 = 4 VGPR
typedef __attribute__((ext_vector_type(4))) float f32x4;

#define LSTR 40   // LDS row stride in bf16 elements (80 B)

static __device__ __forceinline__ short8 pack8(float4 f0, float4 f1) {
    union { __hip_bfloat162 h[4]; short8 s; } u;
    u.h[0] = __float22bfloat162_rn(make_float2(f0.x, f0.y));
    u.h[1] = __float22bfloat162_rn(make_float2(f0.z, f0.w));
    u.h[2] = __float22bfloat162_rn(make_float2(f1.x, f1.y));
    u.h[3] = __float22bfloat162_rn(make_float2(f1.z, f1.w));
    return u.s;
}

// ===========================================================================
// bf16 MFMA GEMM, 128x128 tile, BK=32, 256 thr (4 waves, 2x2), 4x4 MFMA each.
// C[M,N] = A[M,K] @ W[N,K]^T. M%128==0, K%32==0, N%128==0 here.
// fp32 -> bf16 inline during staging (packed cvt).
// ===========================================================================
__global__ __launch_bounds__(256) void gemm_mfma_bt(
    const float* __restrict__ A, const float* __restrict__ W,
    float* __restrict__ C, int M, int N, int K)
{
    __shared__ short As[128 * LSTR];
    __shared__ short Ws[128 * LSTR];
    const int tid  = threadIdx.x;
    const int lane = tid & 63;
    const int wave = tid >> 6;
    const int m0 = blockIdx.y * 128;
    const int n0 = blockIdx.x * 128;
    const int wm = (wave >> 1) * 64;
    const int wn = (wave & 1) * 64;

    f32x4 acc[4][4];
    #pragma unroll
    for (int i = 0; i < 4; ++i)
        #pragma unroll
        for (int j = 0; j < 4; ++j)
            acc[i][j] = (f32x4){0.f, 0.f, 0.f, 0.f};

    const int srow  = tid >> 2;
    const int skoff = (tid & 3) * 8;
    const int frow  = lane & 15;
    const int fkoff = (lane >> 4) * 8;

    for (int k0 = 0; k0 < K; k0 += 32) {
        #pragma unroll
        for (int p = 0; p < 2; ++p) {
            int row = srow + p * 64;
            const float* sa = A + (size_t)(m0 + row) * K + k0 + skoff;
            *(short8*)(As + row * LSTR + skoff) =
                pack8(*(const float4*)sa, *(const float4*)(sa + 4));
            const float* sw = W + (size_t)(n0 + row) * K + k0 + skoff;
            *(short8*)(Ws + row * LSTR + skoff) =
                pack8(*(const float4*)sw, *(const float4*)(sw + 4));
        }
        __syncthreads();

        short8 af[4], bf[4];
        #pragma unroll
        for (int i = 0; i < 4; ++i)
            af[i] = *(const short8*)(As + (wm + i * 16 + frow) * LSTR + fkoff);
        #pragma unroll
        for (int j = 0; j < 4; ++j)
            bf[j] = *(const short8*)(Ws + (wn + j * 16 + frow) * LSTR + fkoff);
        #pragma unroll
        for (int i = 0; i < 4; ++i)
            #pragma unroll
            for (int j = 0; j < 4; ++j)
                acc[i][j] = __builtin_amdgcn_mfma_f32_16x16x32_bf16(af[i], bf[j], acc[i][j], 0, 0, 0);
        __syncthreads();
    }

    const int cl = lane & 15;
    const int rq = (lane >> 4) * 4;
    #pragma unroll
    for (int i = 0; i < 4; ++i) {
        #pragma unroll
        for (int j = 0; j < 4; ++j) {
            int gc = n0 + wn + j * 16 + cl;
            int gr = m0 + wm + i * 16 + rq;
            #pragma unroll
            for (int r = 0; r < 4; ++r)
                C[(size_t)(gr + r) * N + gc] = acc[i][j][r];
        }
    }
}

// ===========================================================================
// Skinny bf16 MFMA: tile 128(M) x 64(N), BK=32, 256 thr; wave w owns rows
// w*32..w*32+31 (2 m-frags) x all 64 cols (4 n-frags).
// C[128,N] = A1@W1^T (+ A2@W2^T if npair==2) + bias1 (+bias2). N bounds-checked.
// ===========================================================================
__global__ __launch_bounds__(256) void gemm_mfma_skinny(
    const float* __restrict__ A1, const float* __restrict__ W1,
    const float* __restrict__ A2, const float* __restrict__ W2,
    const float* __restrict__ bias1, const float* __restrict__ bias2,
    float* __restrict__ C, int N, int K, int npair)
{
    __shared__ short As[128 * LSTR];
    __shared__ short Ws[64 * LSTR];
    const int tid  = threadIdx.x;
    const int lane = tid & 63;
    const int wave = tid >> 6;
    const int n0 = blockIdx.x * 64;
    const int wm = wave * 32;

    f32x4 acc[2][4];
    #pragma unroll
    for (int i = 0; i < 2; ++i)
        #pragma unroll
        for (int j = 0; j < 4; ++j)
            acc[i][j] = (f32x4){0.f, 0.f, 0.f, 0.f};

    const int srow  = tid >> 2;          // 0..63
    const int skoff = (tid & 3) * 8;
    const int frow  = lane & 15;
    const int fkoff = (lane >> 4) * 8;

    for (int pair = 0; pair < npair; ++pair) {
        const float* A = pair ? A2 : A1;
        const float* W = pair ? W2 : W1;
        for (int k0 = 0; k0 < K; k0 += 32) {
            #pragma unroll
            for (int p = 0; p < 2; ++p) {
                int row = srow + p * 64;
                const float* sa = A + (size_t)row * K + k0 + skoff;
                *(short8*)(As + row * LSTR + skoff) =
                    pack8(*(const float4*)sa, *(const float4*)(sa + 4));
            }
            {
                int n = n0 + srow;
                short8 v = (short8){0,0,0,0,0,0,0,0};
                if (n < N) {
                    const float* sw = W + (size_t)n * K + k0 + skoff;
                    v = pack8(*(const float4*)sw, *(const float4*)(sw + 4));
                }
                *(short8*)(Ws + srow * LSTR + skoff) = v;
            }
            __syncthreads();

            short8 af[2], bf[4];
            #pragma unroll
            for (int i = 0; i < 2; ++i)
                af[i] = *(const short8*)(As + (wm + i * 16 + frow) * LSTR + fkoff);
            #pragma unroll
            for (int j = 0; j < 4; ++j)
                bf[j] = *(const short8*)(Ws + (j * 16 + frow) * LSTR + fkoff);
            #pragma unroll
            for (int i = 0; i < 2; ++i)
                #pragma unroll
                for (int j = 0; j < 4; ++j)
                    acc[i][j] = __builtin_amdgcn_mfma_f32_16x16x32_bf16(af[i], bf[j], acc[i][j], 0, 0, 0);
            __syncthreads();
        }
    }

    const int cl = lane & 15;
    const int rq = (lane >> 4) * 4;
    #pragma unroll
    for (int j = 0; j < 4; ++j) {
        int gc = n0 + j * 16 + cl;
        if (gc >= N) continue;
        float b = 0.f;
        if (bias1) b += bias1[gc];
        if (bias2) b += bias2[gc];
        #pragma unroll
        for (int i = 0; i < 2; ++i) {
            int gr = wm + i * 16 + rq;
            #pragma unroll
            for (int r = 0; r < 4; ++r)
                C[(size_t)(gr + r) * N + gc] = acc[i][j][r] + b;
        }
    }
}

// ===========================================================================
// Tiny fp32 GEMM: thread-per-output, 16x16 tile. M,N multiples of 16.
// ===========================================================================
static __device__ __forceinline__ void tiny_body(
    const float* __restrict__ A, const float* __restrict__ W,
    float* __restrict__ C, int K, int ldc)
{
    const int tx = threadIdx.x & 15, ty = threadIdx.x >> 4;
    const int n = blockIdx.x * 16 + tx;
    const int m = blockIdx.y * 16 + ty;
    const float4* a = (const float4*)(A + (size_t)m * K);
    const float4* w = (const float4*)(W + (size_t)n * K);
    float acc0 = 0.f, acc1 = 0.f;
    const int k4 = K >> 2;
    for (int k = 0; k < k4; k += 2) {
        float4 av = a[k],     wv = w[k];
        float4 au = a[k + 1], wu = w[k + 1];
        acc0 += av.x * wv.x + av.y * wv.y + av.z * wv.z + av.w * wv.w;
        acc1 += au.x * wu.x + au.y * wu.y + au.z * wu.z + au.w * wu.w;
    }
    C[(size_t)m * ldc + n] = acc0 + acc1;
}

// three h0 projections fused: z selects weight/output. M=128,N=512,K=1024.
__global__ __launch_bounds__(256) void hproj3_kernel(
    const float* __restrict__ h0,
    const float* __restrict__ Wa, const float* __restrict__ Wb, const float* __restrict__ Wc,
    float* __restrict__ oa, float* __restrict__ ob, float* __restrict__ oc)
{
    const float* W; float* o;
    if (blockIdx.z == 0)      { W = Wa; o = oa; }
    else if (blockIdx.z == 1) { W = Wb; o = ob; }
    else                      { W = Wc; o = oc; }
    tiny_body(h0, W, o, 1024, 512);
}

// two context projections fused into ctx[B,2,C]: z=0 visual(K=1024), z=1 audio(K=512)
__global__ __launch_bounds__(256) void ctxproj_kernel(
    const float* __restrict__ attv, const float* __restrict__ Wv,
    const float* __restrict__ atta, const float* __restrict__ Wa,
    float* __restrict__ ctx)
{
    if (blockIdx.z == 0) tiny_body(attv, Wv, ctx,       1024, 1024);
    else                 tiny_body(atta, Wa, ctx + 512,  512, 1024);
}

__global__ __launch_bounds__(256) void gemm_tiny(
    const float* __restrict__ A, const float* __restrict__ W,
    float* __restrict__ C, int K, int ldc)
{
    tiny_body(A, W, C, K, ldc);
}

// ===========================================================================
// Attention scores: sc[b,t] = sum_c tanh(v1[b,c]+v2[b,t,c]) * W3[c]   (C=512)
// grid (B, T/16), block 256: wave handles 4 t's, lanes split C.
// ===========================================================================
__global__ __launch_bounds__(256) void scores_kernel(
    const float* __restrict__ v1, const float* __restrict__ v2,
    const float* __restrict__ W3, float* __restrict__ sc, int T)
{
    const int C = 512;
    const int b = blockIdx.x, tid = threadIdx.x;
    const int lane = tid & 63, wave = tid >> 6;
    const float* v1b = v1 + (size_t)b * C;
    #pragma unroll
    for (int i = 0; i < 4; ++i) {
        int t = blockIdx.y * 16 + wave * 4 + i;
        const float* v2p = v2 + ((size_t)b * T + t) * C;
        float s = 0.f;
        #pragma unroll
        for (int cc = 0; cc < 8; ++cc) {
            int c = lane + cc * 64;
            s += tanhf(v1b[c] + v2p[c]) * W3[c];
        }
        #pragma unroll
        for (int off = 32; off; off >>= 1) s += __shfl_down(s, off, 64);
        if (lane == 0) sc[(size_t)b * T + t] = s;
    }
}

// ===========================================================================
// Softmax over T + weighted sum: out[b,e] = sum_t softmax(sc[b,:])[t]*enc[b,t,e]
// grid (B, E/256), block 256. T <= 128.
// ===========================================================================
__global__ __launch_bounds__(256) void attend_out_kernel(
    const float* __restrict__ sc, const float* __restrict__ enc,
    float* __restrict__ out, int T, int E)
{
    __shared__ float raw[128];
    __shared__ float ew[128];
    const int b = blockIdx.x, tid = threadIdx.x;
    if (tid < T) raw[tid] = sc[(size_t)b * T + tid];
    __syncthreads();
    float m = -1e30f;
    for (int t = 0; t < T; ++t) m = fmaxf(m, raw[t]);
    if (tid < T) ew[tid] = __expf(raw[tid] - m);
    __syncthreads();
    float sum = 0.f;
    for (int t = 0; t < T; ++t) sum += ew[t];
    const float inv = 1.f / sum;

    const int e = blockIdx.y * 256 + tid;
    const float* encb = enc + (size_t)b * T * E + e;
    float acc = 0.f;
    for (int t = 0; t < T; ++t)
        acc += ew[t] * encb[(size_t)t * E];
    out[(size_t)b * E + e] = acc * inv;
}

// ===========================================================================
// Cross-modal attention + build x = [input | tanh(final_ctx)]
// ===========================================================================
__global__ __launch_bounds__(256) void cross_kernel(
    const float* __restrict__ hc1, const float* __restrict__ v2c,
    const float* __restrict__ W3, const float* __restrict__ ctx,
    const float* __restrict__ inp, float* __restrict__ x)
{
    const int C = 512;
    __shared__ float red[256];
    __shared__ float aw[2];
    const int b = blockIdx.x, tid = threadIdx.x;

    float p0 = 0.f, p1 = 0.f;
    for (int c = tid; c < C; c += 256) {
        float h = hc1[(size_t)b * C + c], w = W3[c];
        p0 += tanhf(h + v2c[(size_t)(b * 2 + 0) * C + c]) * w;
        p1 += tanhf(h + v2c[(size_t)(b * 2 + 1) * C + c]) * w;
    }
    red[tid] = p0; __syncthreads();
    for (int s = 128; s; s >>= 1) { if (tid < s) red[tid] += red[tid + s]; __syncthreads(); }
    float s0 = red[0];
    __syncthreads();
    red[tid] = p1; __syncthreads();
    for (int s = 128; s; s >>= 1) { if (tid < s) red[tid] += red[tid + s]; __syncthreads(); }
    if (tid == 0) {
        float s1 = red[0];
        float m = fmaxf(s0, s1);
        float e0 = __expf(s0 - m), e1 = __expf(s1 - m);
        float inv = 1.f / (e0 + e1);
        aw[0] = e0 * inv; aw[1] = e1 * inv;
    }
    __syncthreads();
    float a0 = aw[0], a1 = aw[1];
    for (int c = tid; c < C; c += 256) {
        float fc = a0 * ctx[(size_t)(b * 2 + 0) * C + c]
                 + a1 * ctx[(size_t)(b * 2 + 1) * C + c];
        x[(size_t)b * 1024 + 512 + c] = tanhf(fc);
        x[(size_t)b * 1024 + c] = inp[(size_t)b * 512 + c];
    }
}

// ===========================================================================
// LSTM pointwise
// ===========================================================================
__global__ __launch_bounds__(256) void lstm_kernel(
    const float* __restrict__ gates, const float* __restrict__ c0,
    float* __restrict__ hout, float* __restrict__ cout)
{
    const int idx = blockIdx.x * 256 + threadIdx.x;   // B*H = 131072
    const int b = idx >> 10, h = idx & 1023;
    const float* g = gates + (size_t)b * 4096;
    float gi = g[h], gf = g[1024 + h], gg = g[2048 + h], go = g[3072 + h];
    float si = 1.f / (1.f + __expf(-gi));
    float sf = 1.f / (1.f + __expf(-gf));
    float so = 1.f / (1.f + __expf(-go));
    float cn = sf * c0[idx] + si * tanhf(gg);
    float hn = so * tanhf(cn);
    cout[idx] = cn;
    hout[idx] = hn;
}

// ---------------------------------------------------------------------------
extern "C" void kernel_launch(void* const* d_in, const int* in_sizes, int n_in,
                              void* d_out, int out_size, void* d_ws, size_t ws_size,
                              hipStream_t stream)
{
    const float* inp    = (const float*)d_in[0];
    const float* encv   = (const float*)d_in[1];
    const float* enca   = (const float*)d_in[2];
    const float* h0     = (const float*)d_in[3];
    const float* c0     = (const float*)d_in[4];
    const float* W_va1  = (const float*)d_in[5];
    const float* W_va2  = (const float*)d_in[6];
    const float* W_va3  = (const float*)d_in[7];
    const float* W_venc = (const float*)d_in[8];
    const float* W_aa1  = (const float*)d_in[9];
    const float* W_aa2  = (const float*)d_in[10];
    const float* W_aa3  = (const float*)d_in[11];
    const float* W_aenc = (const float*)d_in[12];
    const float* W_ca1  = (const float*)d_in[13];
    const float* W_ca2  = (const float*)d_in[14];
    const float* W_ca3  = (const float*)d_in[15];
    const float* W_ih   = (const float*)d_in[16];
    const float* W_hh   = (const float*)d_in[17];
    const float* b_ih   = (const float*)d_in[18];
    const float* b_hh   = (const float*)d_in[19];
    const float* W_out  = (const float*)d_in[20];
    const float* b_out  = (const float*)d_in[21];
    float* out = (float*)d_out;

    float* ws = (float*)d_ws;
    float* v2v  = ws;  ws += (size_t)128 * 64 * 512;    // [B*T_V, C]
    float* v2a  = ws;  ws += (size_t)128 * 128 * 512;   // [B*T_A, C]
    float* hv1  = ws;  ws += 128 * 512;
    float* ha1  = ws;  ws += 128 * 512;
    float* hc1  = ws;  ws += 128 * 512;
    float* attv = ws;  ws += 128 * 1024;
    float* atta = ws;  ws += 128 * 512;
    float* ctx  = ws;  ws += 128 * 2 * 512;
    float* v2c  = ws;  ws += 128 * 2 * 512;
    float* xb   = ws;  ws += 128 * 1024;
    float* gates= ws;  ws += (size_t)128 * 4096;
    float* scv  = ws;  ws += 128 * 64;
    float* sca  = ws;  ws += 128 * 128;

    dim3 blk(256);

    // 1. three h0 projections fused (thread-per-output): grid 32x8x3 = 768 blocks
    hproj3_kernel<<<dim3(32, 8, 3), blk, 0, stream>>>(h0, W_va1, W_aa1, W_ca1, hv1, ha1, hc1);
    // 2/3. encoder projections — bf16 MFMA 128x128 tiles
    gemm_mfma_bt<<<dim3(4, 64),  blk, 0, stream>>>(encv, W_va2, v2v, 8192,  512, 1024);
    gemm_mfma_bt<<<dim3(4, 128), blk, 0, stream>>>(enca, W_aa2, v2a, 16384, 512,  512);
    // 4/5. attention scores: grid (B, T/16)
    scores_kernel<<<dim3(128, 4), blk, 0, stream>>>(hv1, v2v, W_va3, scv, 64);
    scores_kernel<<<dim3(128, 8), blk, 0, stream>>>(ha1, v2a, W_aa3, sca, 128);
    // 6/7. softmax + weighted encoder sum: grid (B, E/256)
    attend_out_kernel<<<dim3(128, 4), blk, 0, stream>>>(scv, encv, attv, 64, 1024);
    attend_out_kernel<<<dim3(128, 2), blk, 0, stream>>>(sca, enca, atta, 128, 512);
    // 8. context projections fused into ctx[B,2,C]: grid 32x8x2
    ctxproj_kernel<<<dim3(32, 8, 2), blk, 0, stream>>>(attv, W_venc, atta, W_aenc, ctx);
    // 9. cross-modal key projection: [256,512] @ [512,512]^T
    gemm_tiny<<<dim3(32, 16), blk, 0, stream>>>(ctx, W_ca2, v2c, 512, 512);
    // 10. cross-modal attention + x build
    cross_kernel<<<128, blk, 0, stream>>>(hc1, v2c, W_ca3, ctx, inp, xb);
    // 11. LSTM gates fused (both GEMMs + both biases): N=4096 -> 64 blocks
    gemm_mfma_skinny<<<dim3(64), blk, 0, stream>>>(xb, W_ih, h0, W_hh, b_ih, b_hh, gates, 4096, 1024, 2);
    // 12. LSTM pointwise -> h_new, c_new in d_out tail
    float* hout = out + 2560000;
    float* cout = out + 2560000 + 131072;
    lstm_kernel<<<512, blk, 0, stream>>>(gates, c0, hout, cout);
    // 13. logits: N=20000 -> 313 blocks
    gemm_mfma_skinny<<<dim3(313), blk, 0, stream>>>(hout, W_out, nullptr, nullptr, b_out, nullptr, out, 20000, 1024, 1);
}

// Round 4
// 457.781 us; speedup vs baseline: 4.4127x; 1.5166x over previous
//
#include <hip/hip_runtime.h>
#include <hip/hip_bf16.h>
#include <cstddef>

typedef __attribute__((ext_vector_type(8))) short short8;   // 8 bf16 = 4 VGPR
typedef __attribute__((ext_vector_type(4))) float f32x4;

#define LSTR 40   // LDS row stride in bf16 elements (80 B)

static __device__ __forceinline__ short8 pack8(float4 f0, float4 f1) {
    union { __hip_bfloat162 h[4]; short8 s; } u;
    u.h[0] = __float22bfloat162_rn(make_float2(f0.x, f0.y));
    u.h[1] = __float22bfloat162_rn(make_float2(f0.z, f0.w));
    u.h[2] = __float22bfloat162_rn(make_float2(f1.x, f1.y));
    u.h[3] = __float22bfloat162_rn(make_float2(f1.z, f1.w));
    return u.s;
}

// ===========================================================================
// Generic split-K bf16 MFMA body: adds A[m0:m0+128, kbeg:kend] @ W^T tile
// into C via atomicAdd. Tile 128(M) x 64(N), BK=32, 256 thr (4 waves, each
// 32 rows x 64 cols). A,W row-major with row stride lda. N bounds-checked.
// C must be zero-initialized (or hold a partial sum).
// ===========================================================================
static __device__ __forceinline__ void sk_body(
    const float* __restrict__ A, int lda,
    const float* __restrict__ W,
    const float* __restrict__ bias, int addbias,
    float* __restrict__ C, int ldc, int N,
    int kbeg, int kend, int n0, int m0)
{
    __shared__ short As[128 * LSTR];
    __shared__ short Ws[64 * LSTR];
    const int tid  = threadIdx.x;
    const int lane = tid & 63;
    const int wave = tid >> 6;
    const int wm = wave * 32;

    f32x4 acc[2][4];
    #pragma unroll
    for (int i = 0; i < 2; ++i)
        #pragma unroll
        for (int j = 0; j < 4; ++j)
            acc[i][j] = (f32x4){0.f, 0.f, 0.f, 0.f};

    const int srow  = tid >> 2;          // 0..63
    const int skoff = (tid & 3) * 8;
    const int frow  = lane & 15;
    const int fkoff = (lane >> 4) * 8;

    for (int k0 = kbeg; k0 < kend; k0 += 32) {
        #pragma unroll
        for (int p = 0; p < 2; ++p) {
            int row = srow + p * 64;
            const float* sa = A + (size_t)(m0 + row) * lda + k0 + skoff;
            *(short8*)(As + row * LSTR + skoff) =
                pack8(*(const float4*)sa, *(const float4*)(sa + 4));
        }
        {
            int n = n0 + srow;
            short8 v = (short8){0,0,0,0,0,0,0,0};
            if (n < N) {
                const float* sw = W + (size_t)n * lda + k0 + skoff;
                v = pack8(*(const float4*)sw, *(const float4*)(sw + 4));
            }
            *(short8*)(Ws + srow * LSTR + skoff) = v;
        }
        __syncthreads();

        short8 af[2], bf[4];
        #pragma unroll
        for (int i = 0; i < 2; ++i)
            af[i] = *(const short8*)(As + (wm + i * 16 + frow) * LSTR + fkoff);
        #pragma unroll
        for (int j = 0; j < 4; ++j)
            bf[j] = *(const short8*)(Ws + (j * 16 + frow) * LSTR + fkoff);
        #pragma unroll
        for (int i = 0; i < 2; ++i)
            #pragma unroll
            for (int j = 0; j < 4; ++j)
                acc[i][j] = __builtin_amdgcn_mfma_f32_16x16x32_bf16(af[i], bf[j], acc[i][j], 0, 0, 0);
        __syncthreads();
    }

    const int cl = lane & 15;
    const int rq = (lane >> 4) * 4;
    #pragma unroll
    for (int j = 0; j < 4; ++j) {
        int gc = n0 + j * 16 + cl;
        if (gc >= N) continue;
        float b = addbias ? bias[gc] : 0.f;
        #pragma unroll
        for (int i = 0; i < 2; ++i) {
            int gr = m0 + wm + i * 16 + rq;
            #pragma unroll
            for (int r = 0; r < 4; ++r)
                atomicAdd(C + (size_t)(gr + r) * ldc + gc, acc[i][j][r] + b);
        }
    }
}

// generic wrapper: grid (ceil(N/64), ksplit, M/128)
__global__ __launch_bounds__(256) void gemm_sk(
    const float* __restrict__ A, const float* __restrict__ W,
    const float* __restrict__ bias, float* __restrict__ C,
    int N, int K, int kchunk, int ldc)
{
    int kbeg = blockIdx.y * kchunk;
    sk_body(A, K, W, bias, bias != nullptr && blockIdx.y == 0,
            C, ldc, N, kbeg, kbeg + kchunk, blockIdx.x * 64, blockIdx.z * 128);
}

// three h0 projections fused: weight/output selected by n-tile. grid (24,4)
__global__ __launch_bounds__(256) void hproj3_mfma(
    const float* __restrict__ h0,
    const float* __restrict__ Wa, const float* __restrict__ Wb, const float* __restrict__ Wc,
    float* __restrict__ hbase)
{
    int n0g = blockIdx.x * 64;
    int wsel = n0g >> 9;
    const float* W = (wsel == 0) ? Wa : (wsel == 1) ? Wb : Wc;
    float* C = hbase + (size_t)wsel * 128 * 512;
    int kbeg = blockIdx.y * 256;
    sk_body(h0, 1024, W, nullptr, 0, C, 512, 512, kbeg, kbeg + 256, n0g & 511, 0);
}

// both context projections fused into ctx[B,2,C]. grid (8,4,2)
__global__ __launch_bounds__(256) void ctxproj_mfma(
    const float* __restrict__ attv, const float* __restrict__ Wv,
    const float* __restrict__ atta, const float* __restrict__ Wa,
    float* __restrict__ ctx)
{
    const float* A; const float* W; float* C; int lda, kb, ke;
    if (blockIdx.z == 0) { A = attv; W = Wv; C = ctx;       lda = 1024; kb = blockIdx.y * 256; ke = kb + 256; }
    else                 { A = atta; W = Wa; C = ctx + 512; lda = 512;  kb = blockIdx.y * 128; ke = kb + 128; }
    sk_body(A, lda, W, nullptr, 0, C, 1024, 512, kb, ke, blockIdx.x * 64, 0);
}

// both LSTM gate GEMMs fused (biases applied in lstm_kernel). grid (64,4)
__global__ __launch_bounds__(256) void gates_mfma(
    const float* __restrict__ xb, const float* __restrict__ W_ih,
    const float* __restrict__ h0, const float* __restrict__ W_hh,
    float* __restrict__ gates)
{
    int pair = blockIdx.y >> 1;
    const float* A = pair ? h0 : xb;
    const float* W = pair ? W_hh : W_ih;
    int kb = (blockIdx.y & 1) * 512;
    sk_body(A, 1024, W, nullptr, 0, gates, 4096, 4096, kb, kb + 512, blockIdx.x * 64, 0);
}

// ===========================================================================
// Encoder projection GEMM with fused attention scores: never materializes v2.
// Tile 128x128 (acc 4x4). Epilogue: p = sum_c tanh(v1[b,c] + v2) * W3[c],
// shfl-reduced over the 16 col-lanes, atomicAdd into sc[b*T+t].
// grid (N/128, M/128). b = row >> tshift.
// ===========================================================================
__global__ __launch_bounds__(256) void gemm_scores(
    const float* __restrict__ A, const float* __restrict__ W,
    const float* __restrict__ v1, const float* __restrict__ W3,
    float* __restrict__ sc, int N, int K, int tshift)
{
    __shared__ short As[128 * LSTR];
    __shared__ short Ws[128 * LSTR];
    const int tid  = threadIdx.x;
    const int lane = tid & 63;
    const int wave = tid >> 6;
    const int m0 = blockIdx.y * 128;
    const int n0 = blockIdx.x * 128;
    const int wm = (wave >> 1) * 64;
    const int wn = (wave & 1) * 64;

    f32x4 acc[4][4];
    #pragma unroll
    for (int i = 0; i < 4; ++i)
        #pragma unroll
        for (int j = 0; j < 4; ++j)
            acc[i][j] = (f32x4){0.f, 0.f, 0.f, 0.f};

    const int srow  = tid >> 2;
    const int skoff = (tid & 3) * 8;
    const int frow  = lane & 15;
    const int fkoff = (lane >> 4) * 8;

    for (int k0 = 0; k0 < K; k0 += 32) {
        #pragma unroll
        for (int p = 0; p < 2; ++p) {
            int row = srow + p * 64;
            const float* sa = A + (size_t)(m0 + row) * K + k0 + skoff;
            *(short8*)(As + row * LSTR + skoff) =
                pack8(*(const float4*)sa, *(const float4*)(sa + 4));
            const float* sw = W + (size_t)(n0 + row) * K + k0 + skoff;
            *(short8*)(Ws + row * LSTR + skoff) =
                pack8(*(const float4*)sw, *(const float4*)(sw + 4));
        }
        __syncthreads();

        short8 af[4], bf[4];
        #pragma unroll
        for (int i = 0; i < 4; ++i)
            af[i] = *(const short8*)(As + (wm + i * 16 + frow) * LSTR + fkoff);
        #pragma unroll
        for (int j = 0; j < 4; ++j)
            bf[j] = *(const short8*)(Ws + (wn + j * 16 + frow) * LSTR + fkoff);
        #pragma unroll
        for (int i = 0; i < 4; ++i)
            #pragma unroll
            for (int j = 0; j < 4; ++j)
                acc[i][j] = __builtin_amdgcn_mfma_f32_16x16x32_bf16(af[i], bf[j], acc[i][j], 0, 0, 0);
        __syncthreads();
    }

    const int cl = lane & 15;
    const int rq = (lane >> 4) * 4;
    #pragma unroll
    for (int i = 0; i < 4; ++i) {
        #pragma unroll
        for (int r = 0; r < 4; ++r) {
            int gr = m0 + wm + i * 16 + rq + r;
            const float* v1row = v1 + (size_t)(gr >> tshift) * 512;
            float p = 0.f;
            #pragma unroll
            for (int j = 0; j < 4; ++j) {
                int gc = n0 + wn + j * 16 + cl;
                p += tanhf(v1row[gc] + acc[i][j][r]) * W3[gc];
            }
            p += __shfl_xor(p, 1, 64);
            p += __shfl_xor(p, 2, 64);
            p += __shfl_xor(p, 4, 64);
            p += __shfl_xor(p, 8, 64);
            if (cl == 0) atomicAdd(sc + gr, p);
        }
    }
}

// ===========================================================================
// Softmax over T + weighted sum: out[b,e] = sum_t softmax(sc[b,:])[t]*enc[b,t,e]
// grid (B, E/256), block 256. T <= 128.
// ===========================================================================
__global__ __launch_bounds__(256) void attend_out_kernel(
    const float* __restrict__ sc, const float* __restrict__ enc,
    float* __restrict__ out, int T, int E)
{
    __shared__ float raw[128];
    __shared__ float ew[128];
    const int b = blockIdx.x, tid = threadIdx.x;
    if (tid < T) raw[tid] = sc[(size_t)b * T + tid];
    __syncthreads();
    float m = -1e30f;
    for (int t = 0; t < T; ++t) m = fmaxf(m, raw[t]);
    if (tid < T) ew[tid] = __expf(raw[tid] - m);
    __syncthreads();
    float sum = 0.f;
    for (int t = 0; t < T; ++t) sum += ew[t];
    const float inv = 1.f / sum;

    const int e = blockIdx.y * 256 + tid;
    const float* encb = enc + (size_t)b * T * E + e;
    float acc = 0.f;
    for (int t = 0; t < T; ++t)
        acc += ew[t] * encb[(size_t)t * E];
    out[(size_t)b * E + e] = acc * inv;
}

// ===========================================================================
// Cross-modal attention + build x = [input | tanh(final_ctx)]
// ===========================================================================
__global__ __launch_bounds__(256) void cross_kernel(
    const float* __restrict__ hc1, const float* __restrict__ v2c,
    const float* __restrict__ W3, const float* __restrict__ ctx,
    const float* __restrict__ inp, float* __restrict__ x)
{
    const int C = 512;
    __shared__ float red[256];
    __shared__ float aw[2];
    const int b = blockIdx.x, tid = threadIdx.x;

    float p0 = 0.f, p1 = 0.f;
    for (int c = tid; c < C; c += 256) {
        float h = hc1[(size_t)b * C + c], w = W3[c];
        p0 += tanhf(h + v2c[(size_t)(b * 2 + 0) * C + c]) * w;
        p1 += tanhf(h + v2c[(size_t)(b * 2 + 1) * C + c]) * w;
    }
    red[tid] = p0; __syncthreads();
    for (int s = 128; s; s >>= 1) { if (tid < s) red[tid] += red[tid + s]; __syncthreads(); }
    float s0 = red[0];
    __syncthreads();
    red[tid] = p1; __syncthreads();
    for (int s = 128; s; s >>= 1) { if (tid < s) red[tid] += red[tid + s]; __syncthreads(); }
    if (tid == 0) {
        float s1 = red[0];
        float m = fmaxf(s0, s1);
        float e0 = __expf(s0 - m), e1 = __expf(s1 - m);
        float inv = 1.f / (e0 + e1);
        aw[0] = e0 * inv; aw[1] = e1 * inv;
    }
    __syncthreads();
    float a0 = aw[0], a1 = aw[1];
    for (int c = tid; c < C; c += 256) {
        float fc = a0 * ctx[(size_t)(b * 2 + 0) * C + c]
                 + a1 * ctx[(size_t)(b * 2 + 1) * C + c];
        x[(size_t)b * 1024 + 512 + c] = tanhf(fc);
        x[(size_t)b * 1024 + c] = inp[(size_t)b * 512 + c];
    }
}

// ===========================================================================
// LSTM pointwise (biases folded in here — gate GEMMs are bias-free split-K)
// ===========================================================================
__global__ __launch_bounds__(256) void lstm_kernel(
    const float* __restrict__ gates, const float* __restrict__ c0,
    const float* __restrict__ b_ih, const float* __restrict__ b_hh,
    float* __restrict__ hout, float* __restrict__ cout)
{
    const int idx = blockIdx.x * 256 + threadIdx.x;   // B*H = 131072
    const int b = idx >> 10, h = idx & 1023;
    const float* g = gates + (size_t)b * 4096;
    float gi = g[h]        + b_ih[h]        + b_hh[h];
    float gf = g[1024 + h] + b_ih[1024 + h] + b_hh[1024 + h];
    float gg = g[2048 + h] + b_ih[2048 + h] + b_hh[2048 + h];
    float go = g[3072 + h] + b_ih[3072 + h] + b_hh[3072 + h];
    float si = 1.f / (1.f + __expf(-gi));
    float sf = 1.f / (1.f + __expf(-gf));
    float so = 1.f / (1.f + __expf(-go));
    float cn = sf * c0[idx] + si * tanhf(gg);
    float hn = so * tanhf(cn);
    cout[idx] = cn;
    hout[idx] = hn;
}

// ---------------------------------------------------------------------------
extern "C" void kernel_launch(void* const* d_in, const int* in_sizes, int n_in,
                              void* d_out, int out_size, void* d_ws, size_t ws_size,
                              hipStream_t stream)
{
    const float* inp    = (const float*)d_in[0];
    const float* encv   = (const float*)d_in[1];
    const float* enca   = (const float*)d_in[2];
    const float* h0     = (const float*)d_in[3];
    const float* c0     = (const float*)d_in[4];
    const float* W_va1  = (const float*)d_in[5];
    const float* W_va2  = (const float*)d_in[6];
    const float* W_va3  = (const float*)d_in[7];
    const float* W_venc = (const float*)d_in[8];
    const float* W_aa1  = (const float*)d_in[9];
    const float* W_aa2  = (const float*)d_in[10];
    const float* W_aa3  = (const float*)d_in[11];
    const float* W_aenc = (const float*)d_in[12];
    const float* W_ca1  = (const float*)d_in[13];
    const float* W_ca2  = (const float*)d_in[14];
    const float* W_ca3  = (const float*)d_in[15];
    const float* W_ih   = (const float*)d_in[16];
    const float* W_hh   = (const float*)d_in[17];
    const float* b_ih   = (const float*)d_in[18];
    const float* b_hh   = (const float*)d_in[19];
    const float* W_out  = (const float*)d_in[20];
    const float* b_out  = (const float*)d_in[21];
    float* out = (float*)d_out;

    // workspace layout: [zero-initialized region | plain scratch]
    float* ws = (float*)d_ws;
    float* hv1  = ws;  ws += 128 * 512;                 // zeroed (atomic targets)
    float* ha1  = ws;  ws += 128 * 512;
    float* hc1  = ws;  ws += 128 * 512;
    float* scv  = ws;  ws += 128 * 64;
    float* sca  = ws;  ws += 128 * 128;
    float* ctx  = ws;  ws += 128 * 2 * 512;
    float* v2c  = ws;  ws += 128 * 2 * 512;
    float* gates= ws;  ws += (size_t)128 * 4096;
    size_t zero_floats = (size_t)(ws - (float*)d_ws);
    float* xb   = ws;  ws += 128 * 1024;
    float* attv = ws;  ws += 128 * 1024;
    float* atta = ws;  ws += 128 * 512;

    dim3 blk(256);

    // 0. zero all atomic-accumulation targets + the logits output region
    hipMemsetAsync(d_ws, 0, zero_floats * sizeof(float), stream);
    hipMemsetAsync(out, 0, (size_t)128 * 20000 * sizeof(float), stream);

    // 1. three h0 projections, one MFMA launch: grid (1536/64, ksplit 4)
    hproj3_mfma<<<dim3(24, 4), blk, 0, stream>>>(h0, W_va1, W_aa1, W_ca1, hv1);
    // 2/3. encoder projections with fused tanh-scores (v2 never materialized)
    gemm_scores<<<dim3(4, 64),  blk, 0, stream>>>(encv, W_va2, hv1, W_va3, scv, 512, 1024, 6);
    gemm_scores<<<dim3(4, 128), blk, 0, stream>>>(enca, W_aa2, ha1, W_aa3, sca, 512,  512, 7);
    // 4/5. softmax + weighted encoder sum
    attend_out_kernel<<<dim3(128, 4), blk, 0, stream>>>(scv, encv, attv, 64, 1024);
    attend_out_kernel<<<dim3(128, 2), blk, 0, stream>>>(sca, enca, atta, 128, 512);
    // 6. both context projections, one launch -> ctx[B,2,C]
    ctxproj_mfma<<<dim3(8, 4, 2), blk, 0, stream>>>(attv, W_venc, atta, W_aenc, ctx);
    // 7. cross-modal key projection: [256,512] @ W_ca2^T, split-K 2, m-tiles 2
    gemm_sk<<<dim3(8, 2, 2), blk, 0, stream>>>(ctx, W_ca2, nullptr, v2c, 512, 512, 256, 512);
    // 8. cross-modal attention + x build
    cross_kernel<<<128, blk, 0, stream>>>(hc1, v2c, W_ca3, ctx, inp, xb);
    // 9. LSTM gates: both GEMMs in one launch, grid (64, 4)
    gates_mfma<<<dim3(64, 4), blk, 0, stream>>>(xb, W_ih, h0, W_hh, gates);
    // 10. LSTM pointwise (+biases) -> h_new, c_new in d_out tail
    float* hout = out + 2560000;
    float* cout = out + 2560000 + 131072;
    lstm_kernel<<<512, blk, 0, stream>>>(gates, c0, b_ih, b_hh, hout, cout);
    // 11. logits: split-K 2, bias added by chunk 0. grid (313, 2)
    gemm_sk<<<dim3(313, 2, 1), blk, 0, stream>>>(hout, W_out, b_out, out, 20000, 1024, 512, 20000);
}

// Round 5
// 397.864 us; speedup vs baseline: 5.0772x; 1.1506x over previous
//
#include <hip/hip_runtime.h>
#include <hip/hip_bf16.h>
#include <cstddef>

typedef __attribute__((ext_vector_type(8))) short short8;   // 8 bf16 = 4 VGPR
typedef __attribute__((ext_vector_type(4))) float f32x4;

#define LSTR 40   // LDS row stride in bf16 elements (80 B)

static __device__ __forceinline__ short8 pack8(float4 f0, float4 f1) {
    union { __hip_bfloat162 h[4]; short8 s; } u;
    u.h[0] = __float22bfloat162_rn(make_float2(f0.x, f0.y));
    u.h[1] = __float22bfloat162_rn(make_float2(f0.z, f0.w));
    u.h[2] = __float22bfloat162_rn(make_float2(f1.x, f1.y));
    u.h[3] = __float22bfloat162_rn(make_float2(f1.z, f1.w));
    return u.s;
}

// ===========================================================================
// Generic split-K bf16 MFMA body: adds A[m0:m0+128, kbeg:kend] @ W^T tile
// into C via atomicAdd. Tile 128(M) x 64(N), BK=32, 256 thr (4 waves, each
// 32 rows x 64 cols). N bounds-checked. C must be zero-initialized.
// ===========================================================================
static __device__ __forceinline__ void sk_body(
    const float* __restrict__ A, int lda,
    const float* __restrict__ W,
    const float* __restrict__ bias, int addbias,
    float* __restrict__ C, int ldc, int N,
    int kbeg, int kend, int n0, int m0)
{
    __shared__ short As[128 * LSTR];
    __shared__ short Ws[64 * LSTR];
    const int tid  = threadIdx.x;
    const int lane = tid & 63;
    const int wave = tid >> 6;
    const int wm = wave * 32;

    f32x4 acc[2][4];
    #pragma unroll
    for (int i = 0; i < 2; ++i)
        #pragma unroll
        for (int j = 0; j < 4; ++j)
            acc[i][j] = (f32x4){0.f, 0.f, 0.f, 0.f};

    const int srow  = tid >> 2;          // 0..63
    const int skoff = (tid & 3) * 8;
    const int frow  = lane & 15;
    const int fkoff = (lane >> 4) * 8;

    for (int k0 = kbeg; k0 < kend; k0 += 32) {
        #pragma unroll
        for (int p = 0; p < 2; ++p) {
            int row = srow + p * 64;
            const float* sa = A + (size_t)(m0 + row) * lda + k0 + skoff;
            *(short8*)(As + row * LSTR + skoff) =
                pack8(*(const float4*)sa, *(const float4*)(sa + 4));
        }
        {
            int n = n0 + srow;
            short8 v = (short8){0,0,0,0,0,0,0,0};
            if (n < N) {
                const float* sw = W + (size_t)n * lda + k0 + skoff;
                v = pack8(*(const float4*)sw, *(const float4*)(sw + 4));
            }
            *(short8*)(Ws + srow * LSTR + skoff) = v;
        }
        __syncthreads();

        short8 af[2], bf[4];
        #pragma unroll
        for (int i = 0; i < 2; ++i)
            af[i] = *(const short8*)(As + (wm + i * 16 + frow) * LSTR + fkoff);
        #pragma unroll
        for (int j = 0; j < 4; ++j)
            bf[j] = *(const short8*)(Ws + (j * 16 + frow) * LSTR + fkoff);
        #pragma unroll
        for (int i = 0; i < 2; ++i)
            #pragma unroll
            for (int j = 0; j < 4; ++j)
                acc[i][j] = __builtin_amdgcn_mfma_f32_16x16x32_bf16(af[i], bf[j], acc[i][j], 0, 0, 0);
        __syncthreads();
    }

    const int cl = lane & 15;
    const int rq = (lane >> 4) * 4;
    #pragma unroll
    for (int j = 0; j < 4; ++j) {
        int gc = n0 + j * 16 + cl;
        if (gc >= N) continue;
        float b = addbias ? bias[gc] : 0.f;
        #pragma unroll
        for (int i = 0; i < 2; ++i) {
            int gr = m0 + wm + i * 16 + rq;
            #pragma unroll
            for (int r = 0; r < 4; ++r)
                atomicAdd(C + (size_t)(gr + r) * ldc + gc, acc[i][j][r] + b);
        }
    }
}

// generic wrapper: grid (ceil(N/64), ksplit, M/128)
__global__ __launch_bounds__(256) void gemm_sk(
    const float* __restrict__ A, const float* __restrict__ W,
    const float* __restrict__ bias, float* __restrict__ C,
    int N, int K, int kchunk, int ldc)
{
    int kbeg = blockIdx.y * kchunk;
    sk_body(A, K, W, bias, bias != nullptr && blockIdx.y == 0,
            C, ldc, N, kbeg, kbeg + kchunk, blockIdx.x * 64, blockIdx.z * 128);
}

// three h0 projections fused: weight/output selected by n-tile. grid (24,8)
__global__ __launch_bounds__(256) void hproj3_mfma(
    const float* __restrict__ h0,
    const float* __restrict__ Wa, const float* __restrict__ Wb, const float* __restrict__ Wc,
    float* __restrict__ hbase)
{
    int n0g = blockIdx.x * 64;
    int wsel = n0g >> 9;
    const float* W = (wsel == 0) ? Wa : (wsel == 1) ? Wb : Wc;
    float* C = hbase + (size_t)wsel * 128 * 512;
    int kbeg = blockIdx.y * 128;
    sk_body(h0, 1024, W, nullptr, 0, C, 512, 512, kbeg, kbeg + 128, n0g & 511, 0);
}

// both context projections fused into ctx[B,2,C]. grid (8,8,2)
__global__ __launch_bounds__(256) void ctxproj_mfma(
    const float* __restrict__ attv, const float* __restrict__ Wv,
    const float* __restrict__ atta, const float* __restrict__ Wa,
    float* __restrict__ ctx)
{
    const float* A; const float* W; float* C; int lda, kb, ke;
    if (blockIdx.z == 0) { A = attv; W = Wv; C = ctx;       lda = 1024; kb = blockIdx.y * 128; ke = kb + 128; }
    else                 { A = atta; W = Wa; C = ctx + 512; lda = 512;  kb = blockIdx.y * 64;  ke = kb + 64;  }
    sk_body(A, lda, W, nullptr, 0, C, 1024, 512, kb, ke, blockIdx.x * 64, 0);
}

// both LSTM gate GEMMs fused (biases applied in lstm_kernel). grid (64,8)
__global__ __launch_bounds__(256) void gates_mfma(
    const float* __restrict__ xb, const float* __restrict__ W_ih,
    const float* __restrict__ h0, const float* __restrict__ W_hh,
    float* __restrict__ gates)
{
    int pair = blockIdx.y >> 2;
    const float* A = pair ? h0 : xb;
    const float* W = pair ? W_hh : W_ih;
    int kb = (blockIdx.y & 3) * 256;
    sk_body(A, 1024, W, nullptr, 0, gates, 4096, 4096, kb, kb + 256, blockIdx.x * 64, 0);
}

// ===========================================================================
// Fused encoder-projection + attention-score kernel, BOTH modalities in one
// launch. Tile 64(M) x 128(N), BK=32, 256 thr (4 waves 2x2: 32m x 64n each).
// Never materializes v2: epilogue computes tanh(v1+v2)*W3, reduces over the
// 16 col-lanes, atomicAdds into sc[row]. N=512 exactly (4 n-tiles, no checks).
// Block order n-major with Mtiles%8==0 -> all n-users of an A-tile land on
// the same XCD (blockIdx%8 XCD round-robin) -> A fetched ~once from HBM.
// grid: 512 visual blocks (n*128+m) then 1024 audio blocks (512 + n*256+m).
// ===========================================================================
__global__ __launch_bounds__(256) void scores_fused(
    const float* __restrict__ encv, const float* __restrict__ W_va2,
    const float* __restrict__ hv1,  const float* __restrict__ W_va3,
    float* __restrict__ scv,
    const float* __restrict__ enca, const float* __restrict__ W_aa2,
    const float* __restrict__ ha1,  const float* __restrict__ W_aa3,
    float* __restrict__ sca)
{
    __shared__ short As[64 * LSTR];
    __shared__ short Ws[128 * LSTR];

    const float *A, *W, *v1, *W3;
    float* sc;
    int K, tshift, n0, m0;
    int idx = blockIdx.x;
    if (idx < 512) {            // visual: M=8192, K=1024, T=64
        n0 = (idx >> 7) * 128;  m0 = (idx & 127) * 64;
        A = encv; W = W_va2; v1 = hv1; W3 = W_va3; sc = scv;
        K = 1024; tshift = 6;
    } else {                    // audio: M=16384, K=512, T=128
        idx -= 512;
        n0 = (idx >> 8) * 128;  m0 = (idx & 255) * 64;
        A = enca; W = W_aa2; v1 = ha1; W3 = W_aa3; sc = sca;
        K = 512; tshift = 7;
    }

    const int tid  = threadIdx.x;
    const int lane = tid & 63;
    const int wave = tid >> 6;
    const int wm = (wave >> 1) * 32;
    const int wn = (wave & 1) * 64;

    f32x4 acc[2][4];
    #pragma unroll
    for (int i = 0; i < 2; ++i)
        #pragma unroll
        for (int j = 0; j < 4; ++j)
            acc[i][j] = (f32x4){0.f, 0.f, 0.f, 0.f};

    const int srow  = tid >> 2;          // 0..63
    const int skoff = (tid & 3) * 8;
    const int frow  = lane & 15;
    const int fkoff = (lane >> 4) * 8;

    for (int k0 = 0; k0 < K; k0 += 32) {
        {   // A: 64 rows x 32 k
            const float* sa = A + (size_t)(m0 + srow) * K + k0 + skoff;
            *(short8*)(As + srow * LSTR + skoff) =
                pack8(*(const float4*)sa, *(const float4*)(sa + 4));
        }
        #pragma unroll
        for (int p = 0; p < 2; ++p) {   // W: 128 rows x 32 k
            int row = srow + p * 64;
            const float* sw = W + (size_t)(n0 + row) * K + k0 + skoff;
            *(short8*)(Ws + row * LSTR + skoff) =
                pack8(*(const float4*)sw, *(const float4*)(sw + 4));
        }
        __syncthreads();

        short8 af[2], bf[4];
        #pragma unroll
        for (int i = 0; i < 2; ++i)
            af[i] = *(const short8*)(As + (wm + i * 16 + frow) * LSTR + fkoff);
        #pragma unroll
        for (int j = 0; j < 4; ++j)
            bf[j] = *(const short8*)(Ws + (wn + j * 16 + frow) * LSTR + fkoff);
        #pragma unroll
        for (int i = 0; i < 2; ++i)
            #pragma unroll
            for (int j = 0; j < 4; ++j)
                acc[i][j] = __builtin_amdgcn_mfma_f32_16x16x32_bf16(af[i], bf[j], acc[i][j], 0, 0, 0);
        __syncthreads();
    }

    // epilogue: p = sum_cols tanh(v1[b,c] + v2) * W3[c]; reduce 16 col-lanes
    const int cl = lane & 15;
    const int rq = (lane >> 4) * 4;
    #pragma unroll
    for (int i = 0; i < 2; ++i) {
        #pragma unroll
        for (int r = 0; r < 4; ++r) {
            int gr = m0 + wm + i * 16 + rq + r;
            const float* v1row = v1 + (size_t)(gr >> tshift) * 512;
            float p = 0.f;
            #pragma unroll
            for (int j = 0; j < 4; ++j) {
                int gc = n0 + wn + j * 16 + cl;
                p += tanhf(v1row[gc] + acc[i][j][r]) * W3[gc];
            }
            p += __shfl_xor(p, 1, 64);
            p += __shfl_xor(p, 2, 64);
            p += __shfl_xor(p, 4, 64);
            p += __shfl_xor(p, 8, 64);
            if (cl == 0) atomicAdd(sc + gr, p);
        }
    }
}

// ===========================================================================
// Softmax over T + weighted sum, both modalities in one launch.
// grid (B, 6): y<4 -> visual e-chunk y; y>=4 -> audio e-chunk y-4.
// ===========================================================================
__global__ __launch_bounds__(256) void attend_out2(
    const float* __restrict__ scv, const float* __restrict__ encv, float* __restrict__ attv,
    const float* __restrict__ sca, const float* __restrict__ enca, float* __restrict__ atta)
{
    const float* sc; const float* enc; float* out;
    int T, E, ec;
    if (blockIdx.y < 4) { sc = scv; enc = encv; out = attv; T = 64;  E = 1024; ec = blockIdx.y; }
    else                { sc = sca; enc = enca; out = atta; T = 128; E = 512;  ec = blockIdx.y - 4; }

    __shared__ float ew[128];
    const int b = blockIdx.x, tid = threadIdx.x;
    __shared__ float raw[128];
    if (tid < T) raw[tid] = sc[(size_t)b * T + tid];
    __syncthreads();
    float m = -1e30f;
    for (int t = 0; t < T; ++t) m = fmaxf(m, raw[t]);
    if (tid < T) ew[tid] = __expf(raw[tid] - m);
    __syncthreads();
    float sum = 0.f;
    for (int t = 0; t < T; ++t) sum += ew[t];
    const float inv = 1.f / sum;

    const int e = ec * 256 + tid;
    const float* encb = enc + (size_t)b * T * E + e;
    float acc = 0.f;
    for (int t = 0; t < T; ++t)
        acc += ew[t] * encb[(size_t)t * E];
    out[(size_t)b * E + e] = acc * inv;
}

// ===========================================================================
// Cross-modal attention + build x = [input | tanh(final_ctx)]
// ===========================================================================
__global__ __launch_bounds__(256) void cross_kernel(
    const float* __restrict__ hc1, const float* __restrict__ v2c,
    const float* __restrict__ W3, const float* __restrict__ ctx,
    const float* __restrict__ inp, float* __restrict__ x)
{
    const int C = 512;
    __shared__ float red[256];
    __shared__ float aw[2];
    const int b = blockIdx.x, tid = threadIdx.x;

    float p0 = 0.f, p1 = 0.f;
    for (int c = tid; c < C; c += 256) {
        float h = hc1[(size_t)b * C + c], w = W3[c];
        p0 += tanhf(h + v2c[(size_t)(b * 2 + 0) * C + c]) * w;
        p1 += tanhf(h + v2c[(size_t)(b * 2 + 1) * C + c]) * w;
    }
    red[tid] = p0; __syncthreads();
    for (int s = 128; s; s >>= 1) { if (tid < s) red[tid] += red[tid + s]; __syncthreads(); }
    float s0 = red[0];
    __syncthreads();
    red[tid] = p1; __syncthreads();
    for (int s = 128; s; s >>= 1) { if (tid < s) red[tid] += red[tid + s]; __syncthreads(); }
    if (tid == 0) {
        float s1 = red[0];
        float m = fmaxf(s0, s1);
        float e0 = __expf(s0 - m), e1 = __expf(s1 - m);
        float inv = 1.f / (e0 + e1);
        aw[0] = e0 * inv; aw[1] = e1 * inv;
    }
    __syncthreads();
    float a0 = aw[0], a1 = aw[1];
    for (int c = tid; c < C; c += 256) {
        float fc = a0 * ctx[(size_t)(b * 2 + 0) * C + c]
                 + a1 * ctx[(size_t)(b * 2 + 1) * C + c];
        x[(size_t)b * 1024 + 512 + c] = tanhf(fc);
        x[(size_t)b * 1024 + c] = inp[(size_t)b * 512 + c];
    }
}

// ===========================================================================
// LSTM pointwise (biases folded in here)
// ===========================================================================
__global__ __launch_bounds__(256) void lstm_kernel(
    const float* __restrict__ gates, const float* __restrict__ c0,
    const float* __restrict__ b_ih, const float* __restrict__ b_hh,
    float* __restrict__ hout, float* __restrict__ cout)
{
    const int idx = blockIdx.x * 256 + threadIdx.x;   // B*H = 131072
    const int b = idx >> 10, h = idx & 1023;
    const float* g = gates + (size_t)b * 4096;
    float gi = g[h]        + b_ih[h]        + b_hh[h];
    float gf = g[1024 + h] + b_ih[1024 + h] + b_hh[1024 + h];
    float gg = g[2048 + h] + b_ih[2048 + h] + b_hh[2048 + h];
    float go = g[3072 + h] + b_ih[3072 + h] + b_hh[3072 + h];
    float si = 1.f / (1.f + __expf(-gi));
    float sf = 1.f / (1.f + __expf(-gf));
    float so = 1.f / (1.f + __expf(-go));
    float cn = sf * c0[idx] + si * tanhf(gg);
    float hn = so * tanhf(cn);
    cout[idx] = cn;
    hout[idx] = hn;
}

// ---------------------------------------------------------------------------
extern "C" void kernel_launch(void* const* d_in, const int* in_sizes, int n_in,
                              void* d_out, int out_size, void* d_ws, size_t ws_size,
                              hipStream_t stream)
{
    const float* inp    = (const float*)d_in[0];
    const float* encv   = (const float*)d_in[1];
    const float* enca   = (const float*)d_in[2];
    const float* h0     = (const float*)d_in[3];
    const float* c0     = (const float*)d_in[4];
    const float* W_va1  = (const float*)d_in[5];
    const float* W_va2  = (const float*)d_in[6];
    const float* W_va3  = (const float*)d_in[7];
    const float* W_venc = (const float*)d_in[8];
    const float* W_aa1  = (const float*)d_in[9];
    const float* W_aa2  = (const float*)d_in[10];
    const float* W_aa3  = (const float*)d_in[11];
    const float* W_aenc = (const float*)d_in[12];
    const float* W_ca1  = (const float*)d_in[13];
    const float* W_ca2  = (const float*)d_in[14];
    const float* W_ca3  = (const float*)d_in[15];
    const float* W_ih   = (const float*)d_in[16];
    const float* W_hh   = (const float*)d_in[17];
    const float* b_ih   = (const float*)d_in[18];
    const float* b_hh   = (const float*)d_in[19];
    const float* W_out  = (const float*)d_in[20];
    const float* b_out  = (const float*)d_in[21];
    float* out = (float*)d_out;

    // workspace layout: [zero-initialized region | plain scratch]
    float* ws = (float*)d_ws;
    float* hv1  = ws;  ws += 128 * 512;                 // zeroed (atomic targets)
    float* ha1  = ws;  ws += 128 * 512;
    float* hc1  = ws;  ws += 128 * 512;
    float* scv  = ws;  ws += 128 * 64;
    float* sca  = ws;  ws += 128 * 128;
    float* ctx  = ws;  ws += 128 * 2 * 512;
    float* v2c  = ws;  ws += 128 * 2 * 512;
    float* gates= ws;  ws += (size_t)128 * 4096;
    size_t zero_floats = (size_t)(ws - (float*)d_ws);
    float* xb   = ws;  ws += 128 * 1024;
    float* attv = ws;  ws += 128 * 1024;
    float* atta = ws;  ws += 128 * 512;

    dim3 blk(256);

    // 0. zero all atomic-accumulation targets + the logits output region
    hipMemsetAsync(d_ws, 0, zero_floats * sizeof(float), stream);
    hipMemsetAsync(out, 0, (size_t)128 * 20000 * sizeof(float), stream);

    // 1. three h0 projections, one MFMA launch: grid (24, 8) = 192 blocks
    hproj3_mfma<<<dim3(24, 8), blk, 0, stream>>>(h0, W_va1, W_aa1, W_ca1, hv1);
    // 2. both encoder projections + fused tanh-scores: 1536 blocks, one launch
    scores_fused<<<dim3(1536), blk, 0, stream>>>(encv, W_va2, hv1, W_va3, scv,
                                                 enca, W_aa2, ha1, W_aa3, sca);
    // 3. softmax + weighted encoder sum, both modalities: grid (128, 6)
    attend_out2<<<dim3(128, 6), blk, 0, stream>>>(scv, encv, attv, sca, enca, atta);
    // 4. both context projections -> ctx[B,2,C]: grid (8,8,2) = 128 blocks
    ctxproj_mfma<<<dim3(8, 8, 2), blk, 0, stream>>>(attv, W_venc, atta, W_aenc, ctx);
    // 5. cross-modal key projection: split-K 4 -> 128 blocks
    gemm_sk<<<dim3(8, 4, 2), blk, 0, stream>>>(ctx, W_ca2, nullptr, v2c, 512, 512, 128, 512);
    // 6. cross-modal attention + x build
    cross_kernel<<<128, blk, 0, stream>>>(hc1, v2c, W_ca3, ctx, inp, xb);
    // 7. LSTM gates: both GEMMs, split-K 4 each: grid (64, 8) = 512 blocks
    gates_mfma<<<dim3(64, 8), blk, 0, stream>>>(xb, W_ih, h0, W_hh, gates);
    // 8. LSTM pointwise (+biases) -> h_new, c_new in d_out tail
    float* hout = out + 2560000;
    float* cout = out + 2560000 + 131072;
    lstm_kernel<<<512, blk, 0, stream>>>(gates, c0, b_ih, b_hh, hout, cout);
    // 9. logits: split-K 2, bias added by chunk 0. grid (313, 2) = 626 blocks
    gemm_sk<<<dim3(313, 2, 1), blk, 0, stream>>>(hout, W_out, b_out, out, 20000, 1024, 512, 20000);
}